// Round 13
// baseline (1534.402 us; speedup 1.0000x reference)
//
#include <hip/hip_runtime.h>
#include <cstdint>
#include <cstddef>

// ---------------------------------------------------------------------------
// Block_Attention, MI355X. fp16 2-way split (3 MFMA passes) for score path;
// single-pass fp16 for V. R13:
//  - KQ: R8-proven gemm8 (16x16 MFMA, in-phase 8-phase schedule, dbuf).
//  - V: NEW single-buffer gemm1b: LDS 64KB -> 2 blocks/CU co-resident;
//    per tile {8 GLD; vmcnt(0); bar; 4 read/lgkm/MFMA phases (no internal
//    barriers); bar}. Cross-block overlap hides the vmcnt(0) stall (m114).
//    Unfused (EPI=1) + final_kernel: fused epilogue would need ~160 VGPR,
//    breaking the <=128 needed for 2-block residency.
//  - R12's 32x32 reverted (4-way bank conflict: 32 rows over 8 XOR slots).
// ---------------------------------------------------------------------------

typedef _Float16 f16_t;
typedef __attribute__((ext_vector_type(8))) _Float16 f16x8;
typedef __attribute__((ext_vector_type(4))) _Float16 f16x4;
typedef __attribute__((ext_vector_type(4))) float f32x4;

#define GLD16(gsrc, ldst) __builtin_amdgcn_global_load_lds( \
    (__attribute__((address_space(1))) void*)(gsrc),        \
    (__attribute__((address_space(3))) void*)(ldst), 16, 0, 0)

#define SBAR() do { __builtin_amdgcn_sched_barrier(0); \
                    __builtin_amdgcn_s_barrier();      \
                    __builtin_amdgcn_sched_barrier(0); } while (0)

#define LGKM0() do { asm volatile("s_waitcnt lgkmcnt(0)" ::: "memory"); \
                     __builtin_amdgcn_sched_barrier(0); } while (0)

template<int N> __device__ __forceinline__ void wvm() {
  if constexpr (N == 0)      asm volatile("s_waitcnt vmcnt(0)" ::: "memory");
  else if constexpr (N == 2) asm volatile("s_waitcnt vmcnt(2)" ::: "memory");
  else if constexpr (N == 4) asm volatile("s_waitcnt vmcnt(4)" ::: "memory");
  __builtin_amdgcn_sched_barrier(0);
}

__device__ __forceinline__ void split16(float v, f16_t& h, f16_t& l) {
  h = (f16_t)v;
  l = (f16_t)(v - (float)h);
}

// ---------------------------------------------------------------------------
// K0: weight prep. rows [0,256)=Wk, [256,512)=Wq, [512,2560)=Wv, [2560,2816)=inc_W
// ---------------------------------------------------------------------------
__global__ __launch_bounds__(256)
void prep_kernel(const float* __restrict__ Wk, const float* __restrict__ bk,
                 const float* __restrict__ Wq, const float* __restrict__ bq,
                 const float* __restrict__ Wv, const float* __restrict__ incW,
                 f16_t* __restrict__ Wkq_a0, f16_t* __restrict__ Wkq_a1,
                 f16_t* __restrict__ Wv_f,
                 f16_t* __restrict__ incW_a0, f16_t* __restrict__ incW_a1,
                 float* __restrict__ bias_kq)
{
  __shared__ float lds[2048];
  const int row = blockIdx.x;
  const int t = threadIdx.x;
  const float* src;
  f16_t* d0;
  f16_t* d1;
  bool permute = true;
  if (row < 256) {
    src = Wk + (size_t)row * 2048; d0 = Wkq_a0 + (size_t)row * 2048; d1 = Wkq_a1 + (size_t)row * 2048;
  } else if (row < 512) {
    src = Wq + (size_t)(row - 256) * 2048; d0 = Wkq_a0 + (size_t)row * 2048; d1 = Wkq_a1 + (size_t)row * 2048;
  } else if (row < 2560) {
    src = Wv + (size_t)(row - 512) * 2048; d0 = Wv_f + (size_t)(row - 512) * 2048; d1 = nullptr;
  } else {
    src = incW + (size_t)(row - 2560) * 2048; d0 = incW_a0 + (size_t)(row - 2560) * 2048;
    d1 = incW_a1 + (size_t)(row - 2560) * 2048; permute = false;
  }
#pragma unroll
  for (int i = 0; i < 8; ++i) lds[i * 256 + t] = src[i * 256 + t];
  if (row < 512 && t == 0) bias_kq[row] = (row < 256) ? bk[row] : bq[row - 256];
  __syncthreads();
#pragma unroll
  for (int i = 0; i < 8; ++i) {
    int kh = i * 256 + t;
    int cp = permute ? (((kh >> 3) & 7) * 256 + (kh & 7) * 32 + (kh >> 6)) : kh;
    float v = lds[cp];
    f16_t hh, ll;
    split16(v, hh, ll);
    d0[kh] = hh;
    if (d1) d1[kh] = ll;
  }
}

// ---------------------------------------------------------------------------
// K1: gather x -> P[patch][j][k̂], k̂ = tq*64 + p1*8 + p2, true c = tq*64 + j.
// ---------------------------------------------------------------------------
__global__ __launch_bounds__(256)
void gather_kernel(const float* __restrict__ x,
                   f16_t* __restrict__ P0, f16_t* __restrict__ P1)
{
  __shared__ float lds[16][8][68];
  const int bid = blockIdx.x;
  const int b = bid >> 8;
  const int ph = (bid >> 5) & 7;
  const int tqc = (bid >> 2) & 7;
  const int qq = bid & 3;
  const int t = threadIdx.x;
  for (int k = 0; k < 4; ++k) {
    const int chunk = qq * 4 + k;
    const int cbase = tqc * 256 + chunk * 16;
#pragma unroll
    for (int it = 0; it < 8; ++it) {
      int flat = it * 1024 + t * 4;
      int ci = flat >> 9, p1 = (flat >> 6) & 7, w = flat & 63;
      const float4 v = *(const float4*)&x[(((size_t)b * 2048 + cbase + ci) * 64 + ph * 8 + p1) * 64 + w];
      *(float4*)&lds[ci][p1][w] = v;
    }
    __syncthreads();
    const int tq = tqc * 4 + qq;
    const int jb = k * 16;
#pragma unroll
    for (int it2 = 0; it2 < 8; ++it2) {
      int flat2 = it2 * 256 + t;
      int g = flat2 & 15, jp = flat2 >> 4;
      int ji = jp >> 3, pw = jp & 7;
      int p1 = g >> 1, w0 = pw * 8 + (g & 1) * 4;
      const float4 v = *(const float4*)&lds[ji][p1][w0];
      float vv[4] = {v.x, v.y, v.z, v.w};
      f16x4 h, l;
#pragma unroll
      for (int u = 0; u < 4; ++u) {
        f16_t hh, ll;
        split16(vv[u], hh, ll);
        h[u] = hh; l[u] = ll;
      }
      size_t pg = (size_t)(b * 64 + ph * 8 + pw);
      size_t dst = pg * 131072 + (size_t)(jb + ji) * 2048 + tq * 64 + g * 4;
      *(f16x4*)&P0[dst] = h;
      *(f16x4*)&P1[dst] = l;
    }
    __syncthreads();
  }
}

// ---------------------------------------------------------------------------
// K1b: x[b, :, h<16, :] -> xT[pix][c] fp16 2-way (transpose via LDS)
// ---------------------------------------------------------------------------
__global__ __launch_bounds__(256)
void xt_kernel(const float* __restrict__ x,
               f16_t* __restrict__ T0, f16_t* __restrict__ T1)
{
  __shared__ float lds[64][65];
  const int bid = blockIdx.x;
  const int b = bid >> 9;
  const int h = (bid >> 5) & 15;
  const int cc = bid & 31;
  const int t = threadIdx.x;
  {
    int ci = t >> 2, w4 = t & 3;
    const float* src = &x[(((size_t)b * 2048 + cc * 64 + ci) * 64 + h) * 64];
#pragma unroll
    for (int it = 0; it < 4; ++it) {
      int w0 = it * 16 + w4 * 4;
      const float4 v = *(const float4*)&src[w0];
      lds[ci][w0 + 0] = v.x; lds[ci][w0 + 1] = v.y;
      lds[ci][w0 + 2] = v.z; lds[ci][w0 + 3] = v.w;
    }
  }
  __syncthreads();
  const int w = t >> 2, cq = t & 3;
  const size_t rowbase = ((size_t)b * 1024 + h * 64 + w) * 2048 + cc * 64 + cq * 16;
  f16x8 H0, H1, L0, L1;
#pragma unroll
  for (int u = 0; u < 8; ++u) {
    f16_t hh, ll;
    split16(lds[cq * 16 + u][w], hh, ll);
    H0[u] = hh; L0[u] = ll;
  }
#pragma unroll
  for (int u = 0; u < 8; ++u) {
    f16_t hh, ll;
    split16(lds[cq * 16 + 8 + u][w], hh, ll);
    H1[u] = hh; L1[u] = ll;
  }
  *(f16x8*)&T0[rowbase] = H0; *(f16x8*)&T0[rowbase + 8] = H1;
  *(f16x8*)&T1[rowbase] = L0; *(f16x8*)&T1[rowbase + 8] = L1;
}

// ---------------------------------------------------------------------------
// 128x128 GEMM (small incidence conv, split-K=3).
// ---------------------------------------------------------------------------
template<int PHASES, int EPI, int SLICES>
__global__ __launch_bounds__(256)
void gemm_kernel(const f16_t* __restrict__ A0, const f16_t* __restrict__ A1,
                 const f16_t* __restrict__ B0, const f16_t* __restrict__ B1,
                 float* __restrict__ Cf, f16_t* __restrict__ Cb,
                 const float* __restrict__ bias, int MB, int ldc)
{
  __shared__ f16_t As[128 * 64];
  __shared__ f16_t Bs[128 * 64];
  const int nwg = gridDim.x;
  const int q = nwg >> 3;
  const int bid = ((int)blockIdx.x & 7) * q + ((int)blockIdx.x >> 3);
  const int tiles = nwg / SLICES;
  const int slice = bid / tiles;
  const int rem = bid % tiles;
  const int nb = rem / MB, mb = rem % MB;
  const int m0 = mb * 128, n0 = nb * 128;
  const int t = threadIdx.x;
  const int lane = t & 63, wv = t >> 6;
  const int wm = (wv >> 1) * 64, wn = (wv & 1) * 64;
  const int l15 = lane & 15, l4 = lane >> 4;

  const f32x4 vzero = {0.f, 0.f, 0.f, 0.f};
  f32x4 acc[4][4];
#pragma unroll
  for (int i = 0; i < 4; ++i)
#pragma unroll
    for (int j = 0; j < 4; ++j) acc[i][j] = vzero;

  constexpr int LOCAL = (32 * PHASES) / SLICES;
  for (int s = 0; s < LOCAL; ++s) {
    const int step = slice * LOCAL + s;
    const int ph = step >> 5;
    const int k0 = (step & 31) << 6;
    const f16_t* Ab = (PHASES == 3 && ph == 2) ? A1 : A0;
    const f16_t* Bb = (PHASES == 3 && ph == 1) ? B1 : B0;
    __syncthreads();
#pragma unroll
    for (int i = 0; i < 4; ++i) {
      int e = i * 2048 + t * 8;
      int row = e >> 6;
      int gl = ((e >> 3) & 7) ^ (row & 7);
      GLD16(Ab + (size_t)(m0 + row) * 2048 + k0 + gl * 8, &As[e]);
    }
#pragma unroll
    for (int i = 0; i < 4; ++i) {
      int e = i * 2048 + t * 8;
      int row = e >> 6;
      int gl = ((e >> 3) & 7) ^ (row & 7);
      GLD16(Bb + (size_t)(n0 + row) * 2048 + k0 + gl * 8, &Bs[e]);
    }
    __syncthreads();
#pragma unroll
    for (int ks = 0; ks < 2; ++ks) {
      f16x8 a[4], bb[4];
#pragma unroll
      for (int i = 0; i < 4; ++i) {
        int r = wm + i * 16 + l15;
        int g = (ks * 4 + l4) ^ (r & 7);
        a[i] = *(const f16x8*)&As[r * 64 + g * 8];
      }
#pragma unroll
      for (int j = 0; j < 4; ++j) {
        int r = wn + j * 16 + l15;
        int g = (ks * 4 + l4) ^ (r & 7);
        bb[j] = *(const f16x8*)&Bs[r * 64 + g * 8];
      }
#pragma unroll
      for (int i = 0; i < 4; ++i)
#pragma unroll
        for (int j = 0; j < 4; ++j)
          acc[i][j] = __builtin_amdgcn_mfma_f32_16x16x32_f16(a[i], bb[j], acc[i][j], 0, 0, 0);
    }
  }

  float* Cp = Cf + (size_t)slice * (size_t)MB * 128 * (size_t)ldc;
#pragma unroll
  for (int i = 0; i < 4; ++i) {
#pragma unroll
    for (int j = 0; j < 4; ++j) {
      int nloc = n0 + wn + j * 16 + l15;
#pragma unroll
      for (int r = 0; r < 4; ++r) {
        int m = m0 + wm + i * 16 + l4 * 4 + r;
        float bsv = (SLICES == 1 || slice == 0) ? bias[m] : 0.f;
        Cp[(size_t)m * ldc + nloc] = acc[i][j][r] + bsv;
      }
    }
  }
}

// ---------------------------------------------------------------------------
// gemm8 (R8-proven, 16x16): double-buffered 8-phase schedule. Used for KQ.
// Per tile t: P0{rdA0,rdB0; stageA(t+1,0); bar; lgkm0; mfma00; bar}
//             P1{rdB1; stageA(t+1,1); bar; lgkm0; mfma01; bar}
//             P2{rdA1; stageB(t+2,0); bar; lgkm0; mfma10; bar}
//             P3{stageB(t+2,1); vmcnt(2GB|0); bar; mfma11; bar}
// ---------------------------------------------------------------------------
#define RDA(dst, RH) \
  _Pragma("unroll") for (int i = 0; i < MIQ; ++i) \
  _Pragma("unroll") for (int ks = 0; ks < 2; ++ks) { \
    int r = wm * WTM + (RH) * (WTM / 2) + i * 16 + l15; \
    dst[i][ks] = *(const f16x8*)&lds[cb + r * 64 + (((ks * 4 + l4) ^ (r & 7)) << 3)]; \
  }
#define RDB(dst, CH) \
  _Pragma("unroll") for (int j = 0; j < NJQ; ++j) \
  _Pragma("unroll") for (int ks = 0; ks < 2; ++ks) { \
    int r = wn * WTN + (CH) * (WTN / 2) + j * 16 + l15; \
    dst[j][ks] = *(const f16x8*)&lds[cb + BBASE + r * 64 + (((ks * 4 + l4) ^ (r & 7)) << 3)]; \
  }
#define QMFMA(AR, BR, RH, CH) do { \
  __builtin_amdgcn_s_setprio(1); \
  _Pragma("unroll") for (int ks = 0; ks < 2; ++ks) \
  _Pragma("unroll") for (int i = 0; i < MIQ; ++i) \
  _Pragma("unroll") for (int j = 0; j < NJQ; ++j) \
    acc[(RH) * MIQ + i][(CH) * NJQ + j] = __builtin_amdgcn_mfma_f32_16x16x32_f16( \
        AR[i][ks], BR[j][ks], acc[(RH) * MIQ + i][(CH) * NJQ + j], 0, 0, 0); \
  __builtin_amdgcn_s_setprio(0); } while (0)

template<int NPH, int BM, int BN, int WM, int WN, int MBT>
__global__ __launch_bounds__(512, 2)
void gemm8_kernel(const f16_t* __restrict__ A0f, const f16_t* __restrict__ A1f,
                  const f16_t* __restrict__ B0f, const f16_t* __restrict__ B1f,
                  float* __restrict__ Cf, const float* __restrict__ bias, int ldc)
{
  constexpr int WTM = BM / WM, WTN = BN / WN;
  constexpr int MIQ = WTM / 32, NJQ = WTN / 32;
  constexpr int GA = BM / 128, GB = BN / 128;
  constexpr int BBASE = BM * 64;
  constexpr int BUF = (BM + BN) * 64;
  constexpr int NT = 32 * NPH;
  constexpr int VW = 2 * GB;
  __shared__ f16_t lds[2 * BUF];

  const int nwg = gridDim.x;
  const int q = nwg >> 3;
  const int bid = ((int)blockIdx.x & 7) * q + ((int)blockIdx.x >> 3);
  const int mb = bid % MBT, nb = bid / MBT;
  const int m0 = mb * BM, n0 = nb * BN;
  const int tid = threadIdx.x;
  const int lane = tid & 63;
  const int wv = tid >> 6;
  const int wm = wv / WN, wn = wv % WN;
  const int l15 = lane & 15, l4 = lane >> 4;

  auto stageA = [&](int tt, int rg) {
    if (tt >= NT) return;
    const f16_t* s = (NPH == 3 && (tt >> 5) == 2) ? A1f : A0f;
    const int g0 = m0 + rg * (BM / 2);
    const int base = (tt & 1) * BUF + rg * (BM / 2) * 64;
    const int k0 = (tt & 31) << 6;
#pragma unroll
    for (int i = 0; i < GA; ++i) {
      int idx = i * 4096 + tid * 8;
      int r = idx >> 6, sl = (idx >> 3) & 7;
      GLD16(s + (size_t)(g0 + r) * 2048 + k0 + ((sl ^ (r & 7)) << 3), &lds[base + idx]);
    }
  };
  auto stageB = [&](int tt, int rg) {
    if (tt >= NT) return;
    const f16_t* s = (NPH == 3 && (tt >> 5) == 1) ? B1f : B0f;
    const int g0 = n0 + rg * (BN / 2);
    const int base = (tt & 1) * BUF + BBASE + rg * (BN / 2) * 64;
    const int k0 = (tt & 31) << 6;
#pragma unroll
    for (int i = 0; i < GB; ++i) {
      int idx = i * 4096 + tid * 8;
      int r = idx >> 6, sl = (idx >> 3) & 7;
      GLD16(s + (size_t)(g0 + r) * 2048 + k0 + ((sl ^ (r & 7)) << 3), &lds[base + idx]);
    }
  };

  const f32x4 vzero = {0.f, 0.f, 0.f, 0.f};
  f32x4 acc[WTM / 16][WTN / 16];
#pragma unroll
  for (int i = 0; i < WTM / 16; ++i)
#pragma unroll
    for (int j = 0; j < WTN / 16; ++j) acc[i][j] = vzero;

  stageA(0, 0); stageA(0, 1); stageB(0, 0); stageB(0, 1);
  stageB(1, 0); stageB(1, 1);
  wvm<VW>();
  SBAR();

  for (int tt = 0; tt < NT; ++tt) {
    const int cb = (tt & 1) * BUF;
    f16x8 a0[MIQ][2], a1[MIQ][2], b0[NJQ][2], b1[NJQ][2];
    RDA(a0, 0); RDB(b0, 0);
    stageA(tt + 1, 0);
    SBAR(); LGKM0();
    QMFMA(a0, b0, 0, 0);
    SBAR();
    RDB(b1, 1);
    stageA(tt + 1, 1);
    SBAR(); LGKM0();
    QMFMA(a0, b1, 0, 1);
    SBAR();
    RDA(a1, 1);
    stageB(tt + 2, 0);
    SBAR(); LGKM0();
    QMFMA(a1, b0, 1, 0);
    SBAR();
    stageB(tt + 2, 1);
    if (tt < NT - 2) { wvm<VW>(); } else { wvm<0>(); }
    SBAR();
    QMFMA(a1, b1, 1, 1);
    SBAR();
  }

#pragma unroll
  for (int i = 0; i < WTM / 16; ++i) {
#pragma unroll
    for (int j = 0; j < WTN / 16; ++j) {
      int ncol = n0 + wn * WTN + j * 16 + l15;
#pragma unroll
      for (int r = 0; r < 4; ++r) {
        int m = m0 + wm * WTM + i * 16 + l4 * 4 + r;
        Cf[(size_t)m * ldc + ncol] = acc[i][j][r] + bias[m];
      }
    }
  }
}

// ---------------------------------------------------------------------------
// gemm1b: single-buffer 256x256 V GEMM. LDS 64KB -> 2 blocks/CU; per tile
// {8 GLD; vmcnt(0); bar; 4 quadrant phases with lgkm0 only (no internal
// barriers — single buffer, data stable after the tile barrier); bar}.
// Cross-block waves hide the vmcnt stall. Out: fp16 V [patch][m][pixel].
// ---------------------------------------------------------------------------
__global__ __launch_bounds__(512, 4)
void gemm1b_kernel(const f16_t* __restrict__ Af, const f16_t* __restrict__ Bf,
                   f16_t* __restrict__ Cb, const float* __restrict__ bias)
{
  constexpr int WTM = 128, WTN = 64, MIQ = 4, NJQ = 2;
  constexpr int BBASE = 16384;
  __shared__ f16_t lds[32768];
  const int nwg = gridDim.x;   // 512
  const int q = nwg >> 3;
  const int bid = ((int)blockIdx.x & 7) * q + ((int)blockIdx.x >> 3);
  const int mb = bid & 7, nb = bid >> 3;   // MBT=8, m fastest
  const int m0 = mb * 256, n0 = nb * 256;
  const int tid = threadIdx.x;
  const int lane = tid & 63;
  const int wv = tid >> 6;
  const int wm = wv >> 2, wn = wv & 3;     // WM=2, WN=4
  const int l15 = lane & 15, l4 = lane >> 4;
  const int cb = 0;

  const f32x4 vzero = {0.f, 0.f, 0.f, 0.f};
  f32x4 acc[8][4];
#pragma unroll
  for (int i = 0; i < 8; ++i)
#pragma unroll
    for (int j = 0; j < 4; ++j) acc[i][j] = vzero;

  for (int tt = 0; tt < 32; ++tt) {
    const int k0 = tt << 6;
#pragma unroll
    for (int i = 0; i < 4; ++i) {
      int idx = i * 4096 + tid * 8;
      int r = idx >> 6, sl = (idx >> 3) & 7;
      GLD16(Af + (size_t)(m0 + r) * 2048 + k0 + ((sl ^ (r & 7)) << 3), &lds[idx]);
    }
#pragma unroll
    for (int i = 0; i < 4; ++i) {
      int idx = i * 4096 + tid * 8;
      int r = idx >> 6, sl = (idx >> 3) & 7;
      GLD16(Bf + (size_t)(n0 + r) * 2048 + k0 + ((sl ^ (r & 7)) << 3), &lds[BBASE + idx]);
    }
    wvm<0>();
    SBAR();
    f16x8 a0[MIQ][2], a1[MIQ][2], b0[NJQ][2], b1[NJQ][2];
    RDA(a0, 0); RDB(b0, 0);
    LGKM0();
    QMFMA(a0, b0, 0, 0);
    RDB(b1, 1);
    LGKM0();
    QMFMA(a0, b1, 0, 1);
    RDA(a1, 1);
    LGKM0();
    QMFMA(a1, b0, 1, 0);
    QMFMA(a1, b1, 1, 1);
    SBAR();
  }

#pragma unroll
  for (int i = 0; i < 8; ++i) {
#pragma unroll
    for (int j = 0; j < 4; ++j) {
      int ncol = n0 + wn * WTN + j * 16 + l15;
#pragma unroll
      for (int r = 0; r < 4; ++r) {
        int m = m0 + wm * WTM + i * 16 + l4 * 4 + r;
        float v = acc[i][j][r] + bias[m];
        int patch = ncol >> 6, jj = ncol & 63;
        Cb[(size_t)patch * 131072 + (size_t)m * 64 + jj] = (f16_t)v;
      }
    }
  }
}

// ---------------------------------------------------------------------------
// K2b: BN + relu + 4x4 avg/max pool; sums 3 split-K partials.
// ---------------------------------------------------------------------------
__global__ void pool_kernel(const float* __restrict__ incout,
                            const float* __restrict__ bnmean, const float* __restrict__ bnvar,
                            const float* __restrict__ gamma, const float* __restrict__ beta,
                            float* __restrict__ incf)
{
  const int blk = blockIdx.x;
  const int b = blk >> 8, k = blk & 255;
  const int n = threadIdx.x;
  const int r = n >> 4, cq = n & 15;
  const float sc = gamma[k] * rsqrtf(bnvar[k] + 1e-5f);
  const float sh = beta[k] - bnmean[k] * sc;
  const size_t PSTR = (size_t)256 * 4096;
  const size_t base = (size_t)k * 4096 + b * 1024 + (r * 4) * 64 + cq * 4;
  float sum = 0.f, mx = 0.f;
#pragma unroll
  for (int dr = 0; dr < 4; ++dr)
#pragma unroll
    for (int dw = 0; dw < 4; ++dw) {
      size_t idx = base + dr * 64 + dw;
      float raw = incout[idx] + incout[idx + PSTR] + incout[idx + 2 * PSTR];
      float v = fmaxf(raw * sc + sh, 0.f);
      sum += v; mx = fmaxf(mx, v);
    }
  incf[(size_t)blk * 64 + n] = sum * (1.f / 16.f) + mx;
}

// ---------------------------------------------------------------------------
// K4: Q_block[b,k,x] = sum_n Q[256+k][(b*64+n)*64+x] * incf[b,k,n] (tree)
// ---------------------------------------------------------------------------
__global__ void qblock_kernel(const float* __restrict__ KQ,
                              const float* __restrict__ incf,
                              float* __restrict__ Qb)
{
  const int blk = blockIdx.x;
  const int b = blk >> 8, k = blk & 255;
  const int x = threadIdx.x;
  const float* qrow = KQ + (size_t)(256 + k) * 16384 + (size_t)b * 4096;
  const float* ivec = incf + (size_t)blk * 64;
  float a0 = 0.f, a1 = 0.f, a2 = 0.f, a3 = 0.f;
#pragma unroll
  for (int n = 0; n < 16; ++n) {
    a0 += qrow[n * 64 + x] * ivec[n];
    a1 += qrow[(n + 16) * 64 + x] * ivec[n + 16];
    a2 += qrow[(n + 32) * 64 + x] * ivec[n + 32];
    a3 += qrow[(n + 48) * 64 + x] * ivec[n + 48];
  }
  Qb[(size_t)blk * 64 + x] = (a0 + a1) + (a2 + a3);
}

// ---------------------------------------------------------------------------
// K5: per patch: S = Qb^T K (fp32), softmax over x, A -> fp16 [pg][y][x]
// ---------------------------------------------------------------------------
__global__ __launch_bounds__(256)
void scores_kernel(const float* __restrict__ KQ, const float* __restrict__ Qb,
                   f16_t* __restrict__ Asm)
{
  __shared__ float Qs[64 * 64];
  __shared__ float Ks[64 * 64];
  const int pg = blockIdx.x;
  const int b = pg >> 6;
  const int t = threadIdx.x;
  const int y = t >> 2, xg = t & 3;
  float s[16];
#pragma unroll
  for (int i = 0; i < 16; ++i) s[i] = 0.f;
  for (int kc = 0; kc < 4; ++kc) {
    __syncthreads();
#pragma unroll
    for (int i = 0; i < 16; ++i) {
      int idx = i * 256 + t;
      Qs[idx] = Qb[(size_t)b * 16384 + kc * 4096 + idx];
      int kl = idx >> 6, yy = idx & 63;
      Ks[idx] = KQ[(size_t)(kc * 64 + kl) * 16384 + (size_t)pg * 64 + yy];
    }
    __syncthreads();
    float sc[16];
#pragma unroll
    for (int i = 0; i < 16; ++i) sc[i] = 0.f;
    for (int k = 0; k < 64; ++k) {
      float kv = Ks[k * 64 + y];
      const float4* qr = (const float4*)&Qs[k * 64 + xg * 16];
#pragma unroll
      for (int q4 = 0; q4 < 4; ++q4) {
        float4 qv = qr[q4];
        sc[q4 * 4 + 0] += qv.x * kv;
        sc[q4 * 4 + 1] += qv.y * kv;
        sc[q4 * 4 + 2] += qv.z * kv;
        sc[q4 * 4 + 3] += qv.w * kv;
      }
    }
#pragma unroll
    for (int i = 0; i < 16; ++i) s[i] += sc[i];
  }
  float mx = s[0];
#pragma unroll
  for (int i = 1; i < 16; ++i) mx = fmaxf(mx, s[i]);
  mx = fmaxf(mx, __shfl_xor(mx, 1));
  mx = fmaxf(mx, __shfl_xor(mx, 2));
  float p[16], sum = 0.f;
#pragma unroll
  for (int i = 0; i < 16; ++i) { p[i] = expf(s[i] - mx); sum += p[i]; }
  sum += __shfl_xor(sum, 1);
  sum += __shfl_xor(sum, 2);
  const float rinv = 1.f / sum;
#pragma unroll
  for (int i = 0; i < 16; ++i)
    Asm[(size_t)pg * 4096 + y * 64 + xg * 16 + i] = (f16_t)(p[i] * rinv);
}

// ---------------------------------------------------------------------------
// K7: out[b,c,nl,y] = sum_x V[pg][c][x]*A[pg][y][x] + x_in[b,c,nl,y]
// ---------------------------------------------------------------------------
__global__ __launch_bounds__(256)
void final_kernel(const f16_t* __restrict__ V, const f16_t* __restrict__ Asm,
                  const float* __restrict__ xin, float* __restrict__ out)
{
  __shared__ f16_t Vs[256 * 64];
  __shared__ f16_t Ps[64 * 64];
  const int bid = blockIdx.x;
  const int pg = bid >> 3, cb = bid & 7;
  const int b = pg >> 6, nl = pg & 63;
  const int t = threadIdx.x;
  const int lane = t & 63, wv = t >> 6;
  const int l15 = lane & 15, l4 = lane >> 4;
  const int wm = wv * 64;

#pragma unroll
  for (int i = 0; i < 8; ++i) {
    int e = i * 2048 + t * 8;
    int row = e >> 6;
    int gl = ((e >> 3) & 7) ^ (row & 7);
    GLD16(V + (size_t)pg * 131072 + (size_t)(cb * 256 + row) * 64 + gl * 8, &Vs[e]);
  }
#pragma unroll
  for (int i = 0; i < 2; ++i) {
    int e = i * 2048 + t * 8;
    int row = e >> 6;
    int gl = ((e >> 3) & 7) ^ (row & 7);
    GLD16(Asm + (size_t)pg * 4096 + (size_t)row * 64 + gl * 8, &Ps[e]);
  }
  __syncthreads();

  const f32x4 vzero = {0.f, 0.f, 0.f, 0.f};
  f32x4 acc[4][4];
#pragma unroll
  for (int i = 0; i < 4; ++i)
#pragma unroll
    for (int j = 0; j < 4; ++j) acc[i][j] = vzero;

#pragma unroll
  for (int ks = 0; ks < 2; ++ks) {
    f16x8 a[4], p[4];
#pragma unroll
    for (int i = 0; i < 4; ++i) {
      int r = wm + i * 16 + l15;
      int g = (ks * 4 + l4) ^ (r & 7);
      a[i] = *(const f16x8*)&Vs[r * 64 + g * 8];
    }
#pragma unroll
    for (int j = 0; j < 4; ++j) {
      int r = j * 16 + l15;
      int g = (ks * 4 + l4) ^ (r & 7);
      p[j] = *(const f16x8*)&Ps[r * 64 + g * 8];
    }
#pragma unroll
    for (int i = 0; i < 4; ++i)
#pragma unroll
      for (int j = 0; j < 4; ++j)
        acc[i][j] = __builtin_amdgcn_mfma_f32_16x16x32_f16(a[i], p[j], acc[i][j], 0, 0, 0);
  }

#pragma unroll
  for (int i = 0; i < 4; ++i) {
#pragma unroll
    for (int j = 0; j < 4; ++j) {
      int y = j * 16 + l15;
#pragma unroll
      for (int r = 0; r < 4; ++r) {
        int c = cb * 256 + wm + i * 16 + l4 * 4 + r;
        size_t idx = (((size_t)b * 2048 + c) * 64 + nl) * 64 + y;
        out[idx] = acc[i][j][r] + xin[idx];
      }
    }
  }
}

// ---------------------------------------------------------------------------
// launch
// ---------------------------------------------------------------------------
extern "C" void kernel_launch(void* const* d_in, const int* in_sizes, int n_in,
                              void* d_out, int out_size, void* d_ws, size_t ws_size,
                              hipStream_t stream) {
  const float* x     = (const float*)d_in[0];
  const float* Wk    = (const float*)d_in[1];
  const float* bk    = (const float*)d_in[2];
  const float* Wq    = (const float*)d_in[3];
  const float* bq    = (const float*)d_in[4];
  const float* Wv    = (const float*)d_in[5];
  const float* bv    = (const float*)d_in[6];
  const float* incW  = (const float*)d_in[7];
  const float* incb  = (const float*)d_in[8];
  const float* gamma = (const float*)d_in[9];
  const float* beta  = (const float*)d_in[10];
  const float* bnmean= (const float*)d_in[11];
  const float* bnvar = (const float*)d_in[12];

  char* ws = (char*)d_ws;
  f16_t* Wkq_a0 = (f16_t*)(ws + 0);
  f16_t* Wkq_a1 = (f16_t*)(ws + 2097152);
  f16_t* Wv_f   = (f16_t*)(ws + 4194304);
  f16_t* incW_a0= (f16_t*)(ws + 12582912);
  f16_t* incW_a1= (f16_t*)(ws + 13631488);
  float* biaskq = (float*) (ws + 14680064);
  float* incout = (float*) (ws + 14682112);
  float* incf   = (float*) (ws + 31459328);
  float* Qb     = (float*) (ws + 31721472);
  f16_t* Asm    = (f16_t*)(ws + 31983616);
  float* KQ     = (float*) (ws + 34080768);
  f16_t* xT_a0  = (f16_t*)(ws + 67635200);
  f16_t* xT_a1  = (f16_t*)(ws + 84412416);
  f16_t* P_a0   = (f16_t*)(ws + 101189632);
  f16_t* P_a1   = (f16_t*)(ws + 168298496);
  f16_t* Vbuf   = P_a1;   // V GEMM (1-pass) reads only P_a0 / Wv_f; reuse

  prep_kernel<<<2816, 256, 0, stream>>>(Wk, bk, Wq, bq, Wv, incW,
                                        Wkq_a0, Wkq_a1, Wv_f, incW_a0, incW_a1, biaskq);
  gather_kernel<<<1024, 256, 0, stream>>>(x, P_a0, P_a1);
  xt_kernel<<<2048, 256, 0, stream>>>(x, xT_a0, xT_a1);
  // incidence conv: M=256 (MB=2), N=4096, split-K 3 (128^2 template)
  gemm_kernel<3, 0, 3><<<192, 256, 0, stream>>>(incW_a0, incW_a1, xT_a0, xT_a1,
                                                incout, nullptr, incb, 2, 4096);
  pool_kernel<<<1024, 64, 0, stream>>>(incout, bnmean, bnvar, gamma, beta, incf);
  // K,Q projections: BM=256,BN=128 -> 2 x 128 = 256 blocks, 3 passes (R8)
  gemm8_kernel<3, 256, 128, 4, 2, 2><<<256, 512, 0, stream>>>(
      Wkq_a0, Wkq_a1, P_a0, P_a1, KQ, biaskq, 16384);
  qblock_kernel<<<1024, 64, 0, stream>>>(KQ, incf, Qb);
  scores_kernel<<<256, 256, 0, stream>>>(KQ, Qb, Asm);
  // V projection: single-buffer 256^2, 512 blocks, 2 blocks/CU
  gemm1b_kernel<<<512, 512, 0, stream>>>(Wv_f, P_a0, Vbuf, bv);
  final_kernel<<<2048, 256, 0, stream>>>(Vbuf, Asm, x, (float*)d_out);
}

// Round 14
// 472.637 us; speedup vs baseline: 3.2465x; 3.2465x over previous
//
#include <hip/hip_runtime.h>
#include <cstdint>
#include <cstddef>

// ---------------------------------------------------------------------------
// Block_Attention, MI355X. fp16 2-way split (3 MFMA passes) for score path;
// single-pass fp16 for V. R14 = R8 verbatim (best measured config, 473 us):
//  - gemm8: in-phase 8-phase dbuf schedule (A(t+1)@P0/P1, B(t+2)@P2/P3,
//    vmcnt(2GB)@P3), 16x16 MFMA, XOR-swizzled LDS (0 conflicts).
//  - V GEMM fuses PV (out = V*A^T + x) via wave-private swizzled LDS spill.
//  - Coalesced LDS-transpose gather.
// Eliminated by measurement: deeper prefetch (R9,R11), 32x32 MFMA (R12:
// 4-way bank conflict), single-buffer 2-blk/CU (R13: VGPR cap 64 -> spill).
// ---------------------------------------------------------------------------

typedef _Float16 f16_t;
typedef __attribute__((ext_vector_type(8))) _Float16 f16x8;
typedef __attribute__((ext_vector_type(4))) _Float16 f16x4;
typedef __attribute__((ext_vector_type(4))) float f32x4;

#define GLD16(gsrc, ldst) __builtin_amdgcn_global_load_lds( \
    (__attribute__((address_space(1))) void*)(gsrc),        \
    (__attribute__((address_space(3))) void*)(ldst), 16, 0, 0)

#define SBAR() do { __builtin_amdgcn_sched_barrier(0); \
                    __builtin_amdgcn_s_barrier();      \
                    __builtin_amdgcn_sched_barrier(0); } while (0)

#define LGKM0() do { asm volatile("s_waitcnt lgkmcnt(0)" ::: "memory"); \
                     __builtin_amdgcn_sched_barrier(0); } while (0)

template<int N> __device__ __forceinline__ void wvm() {
  if constexpr (N == 0)      asm volatile("s_waitcnt vmcnt(0)" ::: "memory");
  else if constexpr (N == 2) asm volatile("s_waitcnt vmcnt(2)" ::: "memory");
  else if constexpr (N == 4) asm volatile("s_waitcnt vmcnt(4)" ::: "memory");
  __builtin_amdgcn_sched_barrier(0);
}

__device__ __forceinline__ void split16(float v, f16_t& h, f16_t& l) {
  h = (f16_t)v;
  l = (f16_t)(v - (float)h);
}

// ---------------------------------------------------------------------------
// K0: weight prep. rows [0,256)=Wk, [256,512)=Wq, [512,2560)=Wv, [2560,2816)=inc_W
// ---------------------------------------------------------------------------
__global__ __launch_bounds__(256)
void prep_kernel(const float* __restrict__ Wk, const float* __restrict__ bk,
                 const float* __restrict__ Wq, const float* __restrict__ bq,
                 const float* __restrict__ Wv, const float* __restrict__ incW,
                 f16_t* __restrict__ Wkq_a0, f16_t* __restrict__ Wkq_a1,
                 f16_t* __restrict__ Wv_f,
                 f16_t* __restrict__ incW_a0, f16_t* __restrict__ incW_a1,
                 float* __restrict__ bias_kq)
{
  __shared__ float lds[2048];
  const int row = blockIdx.x;
  const int t = threadIdx.x;
  const float* src;
  f16_t* d0;
  f16_t* d1;
  bool permute = true;
  if (row < 256) {
    src = Wk + (size_t)row * 2048; d0 = Wkq_a0 + (size_t)row * 2048; d1 = Wkq_a1 + (size_t)row * 2048;
  } else if (row < 512) {
    src = Wq + (size_t)(row - 256) * 2048; d0 = Wkq_a0 + (size_t)row * 2048; d1 = Wkq_a1 + (size_t)row * 2048;
  } else if (row < 2560) {
    src = Wv + (size_t)(row - 512) * 2048; d0 = Wv_f + (size_t)(row - 512) * 2048; d1 = nullptr;
  } else {
    src = incW + (size_t)(row - 2560) * 2048; d0 = incW_a0 + (size_t)(row - 2560) * 2048;
    d1 = incW_a1 + (size_t)(row - 2560) * 2048; permute = false;
  }
#pragma unroll
  for (int i = 0; i < 8; ++i) lds[i * 256 + t] = src[i * 256 + t];
  if (row < 512 && t == 0) bias_kq[row] = (row < 256) ? bk[row] : bq[row - 256];
  __syncthreads();
#pragma unroll
  for (int i = 0; i < 8; ++i) {
    int kh = i * 256 + t;
    int cp = permute ? (((kh >> 3) & 7) * 256 + (kh & 7) * 32 + (kh >> 6)) : kh;
    float v = lds[cp];
    f16_t hh, ll;
    split16(v, hh, ll);
    d0[kh] = hh;
    if (d1) d1[kh] = ll;
  }
}

// ---------------------------------------------------------------------------
// K1: gather x -> P[patch][j][k̂], k̂ = tq*64 + p1*8 + p2, true c = tq*64 + j.
// LDS tile transpose: coalesced reads, 128B-run writes.
// ---------------------------------------------------------------------------
__global__ __launch_bounds__(256)
void gather_kernel(const float* __restrict__ x,
                   f16_t* __restrict__ P0, f16_t* __restrict__ P1)
{
  __shared__ float lds[16][8][68];
  const int bid = blockIdx.x;
  const int b = bid >> 8;
  const int ph = (bid >> 5) & 7;
  const int tqc = (bid >> 2) & 7;
  const int qq = bid & 3;
  const int t = threadIdx.x;
  for (int k = 0; k < 4; ++k) {
    const int chunk = qq * 4 + k;
    const int cbase = tqc * 256 + chunk * 16;
#pragma unroll
    for (int it = 0; it < 8; ++it) {
      int flat = it * 1024 + t * 4;
      int ci = flat >> 9, p1 = (flat >> 6) & 7, w = flat & 63;
      const float4 v = *(const float4*)&x[(((size_t)b * 2048 + cbase + ci) * 64 + ph * 8 + p1) * 64 + w];
      *(float4*)&lds[ci][p1][w] = v;
    }
    __syncthreads();
    const int tq = tqc * 4 + qq;
    const int jb = k * 16;
#pragma unroll
    for (int it2 = 0; it2 < 8; ++it2) {
      int flat2 = it2 * 256 + t;
      int g = flat2 & 15, jp = flat2 >> 4;
      int ji = jp >> 3, pw = jp & 7;
      int p1 = g >> 1, w0 = pw * 8 + (g & 1) * 4;
      const float4 v = *(const float4*)&lds[ji][p1][w0];
      float vv[4] = {v.x, v.y, v.z, v.w};
      f16x4 h, l;
#pragma unroll
      for (int u = 0; u < 4; ++u) {
        f16_t hh, ll;
        split16(vv[u], hh, ll);
        h[u] = hh; l[u] = ll;
      }
      size_t pg = (size_t)(b * 64 + ph * 8 + pw);
      size_t dst = pg * 131072 + (size_t)(jb + ji) * 2048 + tq * 64 + g * 4;
      *(f16x4*)&P0[dst] = h;
      *(f16x4*)&P1[dst] = l;
    }
    __syncthreads();
  }
}

// ---------------------------------------------------------------------------
// K1b: x[b, :, h<16, :] -> xT[pix][c] fp16 2-way (transpose via LDS)
// ---------------------------------------------------------------------------
__global__ __launch_bounds__(256)
void xt_kernel(const float* __restrict__ x,
               f16_t* __restrict__ T0, f16_t* __restrict__ T1)
{
  __shared__ float lds[64][65];
  const int bid = blockIdx.x;
  const int b = bid >> 9;
  const int h = (bid >> 5) & 15;
  const int cc = bid & 31;
  const int t = threadIdx.x;
  {
    int ci = t >> 2, w4 = t & 3;
    const float* src = &x[(((size_t)b * 2048 + cc * 64 + ci) * 64 + h) * 64];
#pragma unroll
    for (int it = 0; it < 4; ++it) {
      int w0 = it * 16 + w4 * 4;
      const float4 v = *(const float4*)&src[w0];
      lds[ci][w0 + 0] = v.x; lds[ci][w0 + 1] = v.y;
      lds[ci][w0 + 2] = v.z; lds[ci][w0 + 3] = v.w;
    }
  }
  __syncthreads();
  const int w = t >> 2, cq = t & 3;
  const size_t rowbase = ((size_t)b * 1024 + h * 64 + w) * 2048 + cc * 64 + cq * 16;
  f16x8 H0, H1, L0, L1;
#pragma unroll
  for (int u = 0; u < 8; ++u) {
    f16_t hh, ll;
    split16(lds[cq * 16 + u][w], hh, ll);
    H0[u] = hh; L0[u] = ll;
  }
#pragma unroll
  for (int u = 0; u < 8; ++u) {
    f16_t hh, ll;
    split16(lds[cq * 16 + 8 + u][w], hh, ll);
    H1[u] = hh; L1[u] = ll;
  }
  *(f16x8*)&T0[rowbase] = H0; *(f16x8*)&T0[rowbase + 8] = H1;
  *(f16x8*)&T1[rowbase] = L0; *(f16x8*)&T1[rowbase + 8] = L1;
}

// ---------------------------------------------------------------------------
// 128x128 GEMM (small incidence conv, split-K=3).
// ---------------------------------------------------------------------------
template<int PHASES, int EPI, int SLICES>
__global__ __launch_bounds__(256)
void gemm_kernel(const f16_t* __restrict__ A0, const f16_t* __restrict__ A1,
                 const f16_t* __restrict__ B0, const f16_t* __restrict__ B1,
                 float* __restrict__ Cf, f16_t* __restrict__ Cb,
                 const float* __restrict__ bias, int MB, int ldc)
{
  __shared__ f16_t As[128 * 64];
  __shared__ f16_t Bs[128 * 64];
  const int nwg = gridDim.x;
  const int q = nwg >> 3;
  const int bid = ((int)blockIdx.x & 7) * q + ((int)blockIdx.x >> 3);
  const int tiles = nwg / SLICES;
  const int slice = bid / tiles;
  const int rem = bid % tiles;
  const int nb = rem / MB, mb = rem % MB;
  const int m0 = mb * 128, n0 = nb * 128;
  const int t = threadIdx.x;
  const int lane = t & 63, wv = t >> 6;
  const int wm = (wv >> 1) * 64, wn = (wv & 1) * 64;
  const int l15 = lane & 15, l4 = lane >> 4;

  const f32x4 vzero = {0.f, 0.f, 0.f, 0.f};
  f32x4 acc[4][4];
#pragma unroll
  for (int i = 0; i < 4; ++i)
#pragma unroll
    for (int j = 0; j < 4; ++j) acc[i][j] = vzero;

  constexpr int LOCAL = (32 * PHASES) / SLICES;
  for (int s = 0; s < LOCAL; ++s) {
    const int step = slice * LOCAL + s;
    const int ph = step >> 5;
    const int k0 = (step & 31) << 6;
    const f16_t* Ab = (PHASES == 3 && ph == 2) ? A1 : A0;
    const f16_t* Bb = (PHASES == 3 && ph == 1) ? B1 : B0;
    __syncthreads();
#pragma unroll
    for (int i = 0; i < 4; ++i) {
      int e = i * 2048 + t * 8;
      int row = e >> 6;
      int gl = ((e >> 3) & 7) ^ (row & 7);
      GLD16(Ab + (size_t)(m0 + row) * 2048 + k0 + gl * 8, &As[e]);
    }
#pragma unroll
    for (int i = 0; i < 4; ++i) {
      int e = i * 2048 + t * 8;
      int row = e >> 6;
      int gl = ((e >> 3) & 7) ^ (row & 7);
      GLD16(Bb + (size_t)(n0 + row) * 2048 + k0 + gl * 8, &Bs[e]);
    }
    __syncthreads();
#pragma unroll
    for (int ks = 0; ks < 2; ++ks) {
      f16x8 a[4], bb[4];
#pragma unroll
      for (int i = 0; i < 4; ++i) {
        int r = wm + i * 16 + l15;
        int g = (ks * 4 + l4) ^ (r & 7);
        a[i] = *(const f16x8*)&As[r * 64 + g * 8];
      }
#pragma unroll
      for (int j = 0; j < 4; ++j) {
        int r = wn + j * 16 + l15;
        int g = (ks * 4 + l4) ^ (r & 7);
        bb[j] = *(const f16x8*)&Bs[r * 64 + g * 8];
      }
#pragma unroll
      for (int i = 0; i < 4; ++i)
#pragma unroll
        for (int j = 0; j < 4; ++j)
          acc[i][j] = __builtin_amdgcn_mfma_f32_16x16x32_f16(a[i], bb[j], acc[i][j], 0, 0, 0);
    }
  }

  float* Cp = Cf + (size_t)slice * (size_t)MB * 128 * (size_t)ldc;
#pragma unroll
  for (int i = 0; i < 4; ++i) {
#pragma unroll
    for (int j = 0; j < 4; ++j) {
      int nloc = n0 + wn + j * 16 + l15;
#pragma unroll
      for (int r = 0; r < 4; ++r) {
        int m = m0 + wm + i * 16 + l4 * 4 + r;
        float bsv = (SLICES == 1 || slice == 0) ? bias[m] : 0.f;
        Cp[(size_t)m * ldc + nloc] = acc[i][j][r] + bsv;
      }
    }
  }
}

// ---------------------------------------------------------------------------
// 8-phase deep-pipelined NT GEMM — R6/R8-proven schedule.
// Per tile t: P0{rdA0,rdB0; stageA(t+1,0); bar; lgkm0; mfma00; bar}
//             P1{rdB1; stageA(t+1,1); bar; lgkm0; mfma01; bar}
//             P2{rdA1; stageB(t+2,0); bar; lgkm0; mfma10; bar}
//             P3{stageB(t+2,1); vmcnt(2GB|0); bar; mfma11; bar}
// EPI=0: fp32 +bias. EPI=2 (BN=256, WN=4): fused PV + residual.
// ---------------------------------------------------------------------------
#define RDA(dst, RH) \
  _Pragma("unroll") for (int i = 0; i < MIQ; ++i) \
  _Pragma("unroll") for (int ks = 0; ks < 2; ++ks) { \
    int r = wm * WTM + (RH) * (WTM / 2) + i * 16 + l15; \
    dst[i][ks] = *(const f16x8*)&lds[cb + r * 64 + (((ks * 4 + l4) ^ (r & 7)) << 3)]; \
  }
#define RDB(dst, CH) \
  _Pragma("unroll") for (int j = 0; j < NJQ; ++j) \
  _Pragma("unroll") for (int ks = 0; ks < 2; ++ks) { \
    int r = wn * WTN + (CH) * (WTN / 2) + j * 16 + l15; \
    dst[j][ks] = *(const f16x8*)&lds[cb + BBASE + r * 64 + (((ks * 4 + l4) ^ (r & 7)) << 3)]; \
  }
#define QMFMA(AR, BR, RH, CH) do { \
  __builtin_amdgcn_s_setprio(1); \
  _Pragma("unroll") for (int ks = 0; ks < 2; ++ks) \
  _Pragma("unroll") for (int i = 0; i < MIQ; ++i) \
  _Pragma("unroll") for (int j = 0; j < NJQ; ++j) \
    acc[(RH) * MIQ + i][(CH) * NJQ + j] = __builtin_amdgcn_mfma_f32_16x16x32_f16( \
        AR[i][ks], BR[j][ks], acc[(RH) * MIQ + i][(CH) * NJQ + j], 0, 0, 0); \
  __builtin_amdgcn_s_setprio(0); } while (0)

template<int NPH, int EPI, int BM, int BN, int WM, int WN, int MBT>
__global__ __launch_bounds__(512, 2)
void gemm8_kernel(const f16_t* __restrict__ A0f, const f16_t* __restrict__ A1f,
                  const f16_t* __restrict__ B0f, const f16_t* __restrict__ B1f,
                  float* __restrict__ Cf, const float* __restrict__ bias, int ldc,
                  const f16_t* __restrict__ Amat, const float* __restrict__ Xin,
                  float* __restrict__ Out)
{
  constexpr int WTM = BM / WM, WTN = BN / WN;
  constexpr int MIQ = WTM / 32, NJQ = WTN / 32;
  constexpr int GA = BM / 128, GB = BN / 128;
  constexpr int BBASE = BM * 64;
  constexpr int BUF = (BM + BN) * 64;
  constexpr int NT = 32 * NPH;
  constexpr int VW = 2 * GB;
  __shared__ f16_t lds[2 * BUF];

  const int nwg = gridDim.x;
  const int q = nwg >> 3;
  const int bid = ((int)blockIdx.x & 7) * q + ((int)blockIdx.x >> 3);
  const int mb = bid % MBT, nb = bid / MBT;
  const int m0 = mb * BM, n0 = nb * BN;
  const int tid = threadIdx.x;
  const int lane = tid & 63;
  const int wv = tid >> 6;
  const int wm = wv / WN, wn = wv % WN;
  const int l15 = lane & 15, l4 = lane >> 4;

  auto stageA = [&](int tt, int rg) {
    if (tt >= NT) return;
    const f16_t* s = (NPH == 3 && (tt >> 5) == 2) ? A1f : A0f;
    const int g0 = m0 + rg * (BM / 2);
    const int base = (tt & 1) * BUF + rg * (BM / 2) * 64;
    const int k0 = (tt & 31) << 6;
#pragma unroll
    for (int i = 0; i < GA; ++i) {
      int idx = i * 4096 + tid * 8;
      int r = idx >> 6, sl = (idx >> 3) & 7;
      GLD16(s + (size_t)(g0 + r) * 2048 + k0 + ((sl ^ (r & 7)) << 3), &lds[base + idx]);
    }
  };
  auto stageB = [&](int tt, int rg) {
    if (tt >= NT) return;
    const f16_t* s = (NPH == 3 && (tt >> 5) == 1) ? B1f : B0f;
    const int g0 = n0 + rg * (BN / 2);
    const int base = (tt & 1) * BUF + BBASE + rg * (BN / 2) * 64;
    const int k0 = (tt & 31) << 6;
#pragma unroll
    for (int i = 0; i < GB; ++i) {
      int idx = i * 4096 + tid * 8;
      int r = idx >> 6, sl = (idx >> 3) & 7;
      GLD16(s + (size_t)(g0 + r) * 2048 + k0 + ((sl ^ (r & 7)) << 3), &lds[base + idx]);
    }
  };

  const f32x4 vzero = {0.f, 0.f, 0.f, 0.f};
  f32x4 acc[WTM / 16][WTN / 16];
#pragma unroll
  for (int i = 0; i < WTM / 16; ++i)
#pragma unroll
    for (int j = 0; j < WTN / 16; ++j) acc[i][j] = vzero;

  // prologue: A(0), B(0), B(1); leave B(1) (=VW GLDs) in flight
  stageA(0, 0); stageA(0, 1); stageB(0, 0); stageB(0, 1);
  stageB(1, 0); stageB(1, 1);
  wvm<VW>();
  SBAR();

  for (int tt = 0; tt < NT; ++tt) {
    const int cb = (tt & 1) * BUF;
    f16x8 a0[MIQ][2], a1[MIQ][2], b0[NJQ][2], b1[NJQ][2];
    // P0
    RDA(a0, 0); RDB(b0, 0);
    stageA(tt + 1, 0);
    SBAR(); LGKM0();
    QMFMA(a0, b0, 0, 0);
    SBAR();
    // P1
    RDB(b1, 1);
    stageA(tt + 1, 1);
    SBAR(); LGKM0();
    QMFMA(a0, b1, 0, 1);
    SBAR();
    // P2
    RDA(a1, 1);
    stageB(tt + 2, 0);
    SBAR(); LGKM0();
    QMFMA(a1, b0, 1, 0);
    SBAR();
    // P3
    stageB(tt + 2, 1);
    if (tt < NT - 2) { wvm<VW>(); } else { wvm<0>(); }
    SBAR();
    QMFMA(a1, b1, 1, 1);
    SBAR();
  }

  if constexpr (EPI == 2) {
    // Fused PV + residual. Wave (wm,wn) holds V rows [m0+wm*128,+128) of
    // patch pg = 4*nb+wn. Spill V(+bias) to wave-private swizzled LDS,
    // re-read as MFMA A-fragments; B-fragments = attention rows from Amat.
    f16_t* vl = &lds[wv * 8192];
#pragma unroll
    for (int i = 0; i < WTM / 16; ++i)
#pragma unroll
      for (int j = 0; j < WTN / 16; ++j)
#pragma unroll
        for (int r = 0; r < 4; ++r) {
          int c = i * 16 + l4 * 4 + r;
          int xx = j * 16 + l15;
          float v = acc[i][j][r] + bias[m0 + wm * 128 + c];
          vl[c * 64 + ((((xx >> 3) ^ (c & 7)) << 3) | (xx & 7))] = (f16_t)v;
        }
    const int pg = 4 * nb + wn;
    f16x8 pb[4][2];
#pragma unroll
    for (int j = 0; j < 4; ++j)
#pragma unroll
      for (int ks = 0; ks < 2; ++ks)
        pb[j][ks] = *(const f16x8*)&Amat[(size_t)pg * 4096 + (j * 16 + l15) * 64 + ks * 32 + l4 * 8];
#pragma unroll
    for (int i = 0; i < WTM / 16; ++i)
#pragma unroll
      for (int j = 0; j < WTN / 16; ++j) acc[i][j] = vzero;
#pragma unroll
    for (int i = 0; i < WTM / 16; ++i) {
      f16x8 va[2];
#pragma unroll
      for (int ks = 0; ks < 2; ++ks) {
        int c = i * 16 + l15;
        va[ks] = *(const f16x8*)&vl[c * 64 + (((ks * 4 + l4) ^ (c & 7)) << 3)];
      }
#pragma unroll
      for (int ks = 0; ks < 2; ++ks)
#pragma unroll
        for (int j = 0; j < 4; ++j)
          acc[i][j] = __builtin_amdgcn_mfma_f32_16x16x32_f16(va[ks], pb[j][ks], acc[i][j], 0, 0, 0);
    }
    const int bb = pg >> 6, nl = pg & 63;
    const size_t obase = ((size_t)bb * 2048 + m0 + wm * 128) * 4096 + (size_t)nl * 64;
#pragma unroll
    for (int i = 0; i < WTM / 16; ++i)
#pragma unroll
      for (int j = 0; j < 4; ++j)
#pragma unroll
        for (int r = 0; r < 4; ++r) {
          int c = i * 16 + l4 * 4 + r;
          int y = j * 16 + l15;
          size_t idx = obase + (size_t)c * 4096 + y;
          Out[idx] = acc[i][j][r] + Xin[idx];
        }
  } else {
#pragma unroll
    for (int i = 0; i < WTM / 16; ++i) {
#pragma unroll
      for (int j = 0; j < WTN / 16; ++j) {
        int ncol = n0 + wn * WTN + j * 16 + l15;
#pragma unroll
        for (int r = 0; r < 4; ++r) {
          int m = m0 + wm * WTM + i * 16 + l4 * 4 + r;
          Cf[(size_t)m * ldc + ncol] = acc[i][j][r] + bias[m];
        }
      }
    }
  }
}

// ---------------------------------------------------------------------------
// K2b: BN + relu + 4x4 avg/max pool; sums 3 split-K partials.
// ---------------------------------------------------------------------------
__global__ void pool_kernel(const float* __restrict__ incout,
                            const float* __restrict__ bnmean, const float* __restrict__ bnvar,
                            const float* __restrict__ gamma, const float* __restrict__ beta,
                            float* __restrict__ incf)
{
  const int blk = blockIdx.x;
  const int b = blk >> 8, k = blk & 255;
  const int n = threadIdx.x;
  const int r = n >> 4, cq = n & 15;
  const float sc = gamma[k] * rsqrtf(bnvar[k] + 1e-5f);
  const float sh = beta[k] - bnmean[k] * sc;
  const size_t PSTR = (size_t)256 * 4096;
  const size_t base = (size_t)k * 4096 + b * 1024 + (r * 4) * 64 + cq * 4;
  float sum = 0.f, mx = 0.f;
#pragma unroll
  for (int dr = 0; dr < 4; ++dr)
#pragma unroll
    for (int dw = 0; dw < 4; ++dw) {
      size_t idx = base + dr * 64 + dw;
      float raw = incout[idx] + incout[idx + PSTR] + incout[idx + 2 * PSTR];
      float v = fmaxf(raw * sc + sh, 0.f);
      sum += v; mx = fmaxf(mx, v);
    }
  incf[(size_t)blk * 64 + n] = sum * (1.f / 16.f) + mx;
}

// ---------------------------------------------------------------------------
// K4: Q_block[b,k,x] = sum_n Q[256+k][(b*64+n)*64+x] * incf[b,k,n] (tree)
// ---------------------------------------------------------------------------
__global__ void qblock_kernel(const float* __restrict__ KQ,
                              const float* __restrict__ incf,
                              float* __restrict__ Qb)
{
  const int blk = blockIdx.x;
  const int b = blk >> 8, k = blk & 255;
  const int x = threadIdx.x;
  const float* qrow = KQ + (size_t)(256 + k) * 16384 + (size_t)b * 4096;
  const float* ivec = incf + (size_t)blk * 64;
  float a0 = 0.f, a1 = 0.f, a2 = 0.f, a3 = 0.f;
#pragma unroll
  for (int n = 0; n < 16; ++n) {
    a0 += qrow[n * 64 + x] * ivec[n];
    a1 += qrow[(n + 16) * 64 + x] * ivec[n + 16];
    a2 += qrow[(n + 32) * 64 + x] * ivec[n + 32];
    a3 += qrow[(n + 48) * 64 + x] * ivec[n + 48];
  }
  Qb[(size_t)blk * 64 + x] = (a0 + a1) + (a2 + a3);
}

// ---------------------------------------------------------------------------
// K5: per patch: S = Qb^T K (fp32), softmax over x, A -> fp16 [pg][y][x]
// ---------------------------------------------------------------------------
__global__ __launch_bounds__(256)
void scores_kernel(const float* __restrict__ KQ, const float* __restrict__ Qb,
                   f16_t* __restrict__ Asm)
{
  __shared__ float Qs[64 * 64];
  __shared__ float Ks[64 * 64];
  const int pg = blockIdx.x;
  const int b = pg >> 6;
  const int t = threadIdx.x;
  const int y = t >> 2, xg = t & 3;
  float s[16];
#pragma unroll
  for (int i = 0; i < 16; ++i) s[i] = 0.f;
  for (int kc = 0; kc < 4; ++kc) {
    __syncthreads();
#pragma unroll
    for (int i = 0; i < 16; ++i) {
      int idx = i * 256 + t;
      Qs[idx] = Qb[(size_t)b * 16384 + kc * 4096 + idx];
      int kl = idx >> 6, yy = idx & 63;
      Ks[idx] = KQ[(size_t)(kc * 64 + kl) * 16384 + (size_t)pg * 64 + yy];
    }
    __syncthreads();
    float sc[16];
#pragma unroll
    for (int i = 0; i < 16; ++i) sc[i] = 0.f;
    for (int k = 0; k < 64; ++k) {
      float kv = Ks[k * 64 + y];
      const float4* qr = (const float4*)&Qs[k * 64 + xg * 16];
#pragma unroll
      for (int q4 = 0; q4 < 4; ++q4) {
        float4 qv = qr[q4];
        sc[q4 * 4 + 0] += qv.x * kv;
        sc[q4 * 4 + 1] += qv.y * kv;
        sc[q4 * 4 + 2] += qv.z * kv;
        sc[q4 * 4 + 3] += qv.w * kv;
      }
    }
#pragma unroll
    for (int i = 0; i < 16; ++i) s[i] += sc[i];
  }
  float mx = s[0];
#pragma unroll
  for (int i = 1; i < 16; ++i) mx = fmaxf(mx, s[i]);
  mx = fmaxf(mx, __shfl_xor(mx, 1));
  mx = fmaxf(mx, __shfl_xor(mx, 2));
  float p[16], sum = 0.f;
#pragma unroll
  for (int i = 0; i < 16; ++i) { p[i] = expf(s[i] - mx); sum += p[i]; }
  sum += __shfl_xor(sum, 1);
  sum += __shfl_xor(sum, 2);
  const float rinv = 1.f / sum;
#pragma unroll
  for (int i = 0; i < 16; ++i)
    Asm[(size_t)pg * 4096 + y * 64 + xg * 16 + i] = (f16_t)(p[i] * rinv);
}

// ---------------------------------------------------------------------------
// launch
// ---------------------------------------------------------------------------
extern "C" void kernel_launch(void* const* d_in, const int* in_sizes, int n_in,
                              void* d_out, int out_size, void* d_ws, size_t ws_size,
                              hipStream_t stream) {
  const float* x     = (const float*)d_in[0];
  const float* Wk    = (const float*)d_in[1];
  const float* bk    = (const float*)d_in[2];
  const float* Wq    = (const float*)d_in[3];
  const float* bq    = (const float*)d_in[4];
  const float* Wv    = (const float*)d_in[5];
  const float* bv    = (const float*)d_in[6];
  const float* incW  = (const float*)d_in[7];
  const float* incb  = (const float*)d_in[8];
  const float* gamma = (const float*)d_in[9];
  const float* beta  = (const float*)d_in[10];
  const float* bnmean= (const float*)d_in[11];
  const float* bnvar = (const float*)d_in[12];

  char* ws = (char*)d_ws;
  f16_t* Wkq_a0 = (f16_t*)(ws + 0);
  f16_t* Wkq_a1 = (f16_t*)(ws + 2097152);
  f16_t* Wv_f   = (f16_t*)(ws + 4194304);
  f16_t* incW_a0= (f16_t*)(ws + 12582912);
  f16_t* incW_a1= (f16_t*)(ws + 13631488);
  float* biaskq = (float*) (ws + 14680064);
  float* incout = (float*) (ws + 14682112);
  float* incf   = (float*) (ws + 31459328);
  float* Qb     = (float*) (ws + 31721472);
  f16_t* Asm    = (f16_t*)(ws + 31983616);
  float* KQ     = (float*) (ws + 34080768);
  f16_t* xT_a0  = (f16_t*)(ws + 67635200);
  f16_t* xT_a1  = (f16_t*)(ws + 84412416);
  f16_t* P_a0   = (f16_t*)(ws + 101189632);
  f16_t* P_a1   = (f16_t*)(ws + 168298496);

  prep_kernel<<<2816, 256, 0, stream>>>(Wk, bk, Wq, bq, Wv, incW,
                                        Wkq_a0, Wkq_a1, Wv_f, incW_a0, incW_a1, biaskq);
  gather_kernel<<<1024, 256, 0, stream>>>(x, P_a0, P_a1);
  xt_kernel<<<2048, 256, 0, stream>>>(x, xT_a0, xT_a1);
  // incidence conv: M=256 (MB=2), N=4096, split-K 3 (128^2 template)
  gemm_kernel<3, 0, 3><<<192, 256, 0, stream>>>(incW_a0, incW_a1, xT_a0, xT_a1,
                                                incout, nullptr, incb, 2, 4096);
  pool_kernel<<<1024, 64, 0, stream>>>(incout, bnmean, bnvar, gamma, beta, incf);
  // K,Q projections: BM=256,BN=128 -> 2 x 128 = 256 blocks, 3 passes
  gemm8_kernel<3, 0, 256, 128, 4, 2, 2><<<256, 512, 0, stream>>>(
      Wkq_a0, Wkq_a1, P_a0, P_a1, KQ, biaskq, 16384, nullptr, nullptr, nullptr);
  qblock_kernel<<<1024, 64, 0, stream>>>(KQ, incf, Qb);
  scores_kernel<<<256, 256, 0, stream>>>(KQ, Qb, Asm);
  // V projection + fused PV + residual: BM=256,BN=256 -> 512 blocks
  gemm8_kernel<1, 2, 256, 256, 2, 4, 8><<<512, 512, 0, stream>>>(
      Wv_f, Wv_f, P_a0, P_a0, nullptr, bv, 0, Asm, x, (float*)d_out);
}